// Round 1
// baseline (539.081 us; speedup 1.0000x reference)
//
#include <hip/hip_runtime.h>
#include <hip/hip_bf16.h>
#include <cmath>
#include <type_traits>

#define BC     4
#define SEQ    2048
#define DMODEL 1024
#define NHEAD  16
#define HD     64
#define ASCALE 0.125f

typedef __bf16 bf16x8 __attribute__((ext_vector_type(8)));
typedef float  f32x4  __attribute__((ext_vector_type(4)));

__device__ __forceinline__ f32x4 mfma16x16x32(bf16x8 a, bf16x8 b, f32x4 c) {
    return __builtin_amdgcn_mfma_f32_16x16x32_bf16(a, b, c, 0, 0, 0);
}

// out[M,N] = A[M,K] @ W[N,K]^T + bias[N].  TA in {float,__bf16}, TO in {__bf16,float}.
template <typename TA, typename TO>
__global__ __launch_bounds__(256) void gemm_bt(const TA* __restrict__ A,
                                               const float* __restrict__ W,
                                               const float* __restrict__ bias,
                                               TO* __restrict__ out,
                                               int M, int N, int K) {
    __shared__ __bf16 As[128][40];   // stride 40 (80B): 16B-aligned rows, 2-way banks = free
    __shared__ __bf16 Bs[128][40];
    const int tid = threadIdx.x;
    const int lane = tid & 63;
    const int wid = tid >> 6;
    const int lr = lane & 15;
    const int lg = lane >> 4;
    const int wr = (wid >> 1) * 64;
    const int wc = (wid & 1) * 64;
    const int bm = blockIdx.x * 128;
    const int bn = blockIdx.y * 128;
    const int srow = tid >> 1;
    const int scol = (tid & 1) * 16;

    f32x4 acc[4][4] = {};

    for (int k0 = 0; k0 < K; k0 += 32) {
        bf16x8 a0, a1;
        if constexpr (std::is_same_v<TA, float>) {
            const float* ap = (const float*)A + (size_t)(bm + srow) * K + k0 + scol;
            float4 f0 = ((const float4*)ap)[0];
            float4 f1 = ((const float4*)ap)[1];
            float4 f2 = ((const float4*)ap)[2];
            float4 f3 = ((const float4*)ap)[3];
            a0[0] = (__bf16)f0.x; a0[1] = (__bf16)f0.y; a0[2] = (__bf16)f0.z; a0[3] = (__bf16)f0.w;
            a0[4] = (__bf16)f1.x; a0[5] = (__bf16)f1.y; a0[6] = (__bf16)f1.z; a0[7] = (__bf16)f1.w;
            a1[0] = (__bf16)f2.x; a1[1] = (__bf16)f2.y; a1[2] = (__bf16)f2.z; a1[3] = (__bf16)f2.w;
            a1[4] = (__bf16)f3.x; a1[5] = (__bf16)f3.y; a1[6] = (__bf16)f3.z; a1[7] = (__bf16)f3.w;
        } else {
            const __bf16* ap = (const __bf16*)A + (size_t)(bm + srow) * K + k0 + scol;
            a0 = ((const bf16x8*)ap)[0];
            a1 = ((const bf16x8*)ap)[1];
        }
        const float* wp = W + (size_t)(bn + srow) * K + k0 + scol;
        float4 g0 = ((const float4*)wp)[0];
        float4 g1 = ((const float4*)wp)[1];
        float4 g2 = ((const float4*)wp)[2];
        float4 g3 = ((const float4*)wp)[3];
        bf16x8 b0, b1;
        b0[0] = (__bf16)g0.x; b0[1] = (__bf16)g0.y; b0[2] = (__bf16)g0.z; b0[3] = (__bf16)g0.w;
        b0[4] = (__bf16)g1.x; b0[5] = (__bf16)g1.y; b0[6] = (__bf16)g1.z; b0[7] = (__bf16)g1.w;
        b1[0] = (__bf16)g2.x; b1[1] = (__bf16)g2.y; b1[2] = (__bf16)g2.z; b1[3] = (__bf16)g2.w;
        b1[4] = (__bf16)g3.x; b1[5] = (__bf16)g3.y; b1[6] = (__bf16)g3.z; b1[7] = (__bf16)g3.w;

        *(bf16x8*)&As[srow][scol]     = a0;
        *(bf16x8*)&As[srow][scol + 8] = a1;
        *(bf16x8*)&Bs[srow][scol]     = b0;
        *(bf16x8*)&Bs[srow][scol + 8] = b1;

        __syncthreads();

        bf16x8 af[4], bfg[4];
        #pragma unroll
        for (int m = 0; m < 4; ++m)
            af[m] = *(const bf16x8*)&As[wr + m * 16 + lr][lg * 8];
        #pragma unroll
        for (int n = 0; n < 4; ++n)
            bfg[n] = *(const bf16x8*)&Bs[wc + n * 16 + lr][lg * 8];
        #pragma unroll
        for (int m = 0; m < 4; ++m)
            #pragma unroll
            for (int n = 0; n < 4; ++n)
                acc[m][n] = mfma16x16x32(af[m], bfg[n], acc[m][n]);
        __syncthreads();
    }

    #pragma unroll
    for (int n = 0; n < 4; ++n) {
        const int col = bn + wc + n * 16 + lr;
        const float bb = bias[col];
        #pragma unroll
        for (int m = 0; m < 4; ++m) {
            const int row = bm + wr + m * 16 + lg * 4;
            #pragma unroll
            for (int r = 0; r < 4; ++r) {
                float val = acc[m][n][r] + bb;
                out[(size_t)(row + r) * N + col] = (TO)val;
            }
        }
    }
}

// vt[b][h][hd][s] = v[b][s][h*64+hd]
__global__ __launch_bounds__(256) void transpose_v(const __bf16* __restrict__ v,
                                                   __bf16* __restrict__ vt) {
    __shared__ __bf16 T[64][72];
    const int tid = threadIdx.x;
    const int s0 = blockIdx.x * 64;
    const int h = blockIdx.y;
    const int b = blockIdx.z;
    const int r = tid >> 2;
    const int c0 = (tid & 3) * 16;
    const __bf16* vp = v + (size_t)(b * SEQ + s0 + r) * DMODEL + h * HD + c0;
    *(bf16x8*)&T[r][c0]     = ((const bf16x8*)vp)[0];
    *(bf16x8*)&T[r][c0 + 8] = ((const bf16x8*)vp)[1];
    __syncthreads();
    const int hd = tid >> 2;
    const int sc = (tid & 3) * 16;
    bf16x8 o0, o1;
    #pragma unroll
    for (int j = 0; j < 8; ++j) o0[j] = T[sc + j][hd];
    #pragma unroll
    for (int j = 0; j < 8; ++j) o1[j] = T[sc + 8 + j][hd];
    __bf16* op = vt + ((size_t)(b * NHEAD + h) * HD + hd) * SEQ + s0 + sc;
    ((bf16x8*)op)[0] = o0;
    ((bf16x8*)op)[1] = o1;
}

// Causal flash attention. q,k: [B,S,D] bf16 (head-interleaved). vt: [B,H,HD,S] bf16.
// o: [B,S,D] bf16. mbuf/lbuf: [B,H,S] f32 row stats for the weights pass.
__global__ __launch_bounds__(256) void flash_fwd(const __bf16* __restrict__ q,
                                                 const __bf16* __restrict__ k,
                                                 const __bf16* __restrict__ vt,
                                                 __bf16* __restrict__ o,
                                                 float* __restrict__ mbuf,
                                                 float* __restrict__ lbuf) {
    __shared__ __bf16 Ks[64][72];
    __shared__ __bf16 Vs[64][72];   // transposed: [hd][t]
    __shared__ __bf16 Ps[4][16][72];
    const int tid = threadIdx.x;
    const int lane = tid & 63;
    const int wid = tid >> 6;
    const int lr = lane & 15;
    const int lg = lane >> 4;
    const int qt = blockIdx.x;
    const int h = blockIdx.y;
    const int b = blockIdx.z;
    const int q0 = qt * 64;
    const int qr = q0 + wid * 16;   // this wave's 16 query rows

    bf16x8 qf0, qf1;
    {
        const __bf16* qp = q + (size_t)(b * SEQ + qr + lr) * DMODEL + h * HD + lg * 8;
        qf0 = ((const bf16x8*)qp)[0];
        qf1 = *(const bf16x8*)(qp + 32);
    }

    float m_run[4], l_run[4];
    f32x4 oacc[4] = {};
    #pragma unroll
    for (int r = 0; r < 4; ++r) { m_run[r] = -INFINITY; l_run[r] = 0.f; }

    const int srow = tid >> 2;
    const int sc0 = (tid & 3) * 16;
    const int nt = qt + 1;
    for (int t = 0; t < nt; ++t) {
        const int t0 = t * 64;
        {
            const __bf16* kp = k + (size_t)(b * SEQ + t0 + srow) * DMODEL + h * HD + sc0;
            *(bf16x8*)&Ks[srow][sc0]     = ((const bf16x8*)kp)[0];
            *(bf16x8*)&Ks[srow][sc0 + 8] = ((const bf16x8*)kp)[1];
            const __bf16* vp = vt + ((size_t)(b * NHEAD + h) * HD + srow) * SEQ + t0 + sc0;
            *(bf16x8*)&Vs[srow][sc0]     = ((const bf16x8*)vp)[0];
            *(bf16x8*)&Vs[srow][sc0 + 8] = ((const bf16x8*)vp)[1];
        }
        __syncthreads();

        // S = Q K^T * scale, causal-masked
        f32x4 sc4[4];
        #pragma unroll
        for (int ts = 0; ts < 4; ++ts) {
            bf16x8 kf0 = *(const bf16x8*)&Ks[ts * 16 + lr][lg * 8];
            bf16x8 kf1 = *(const bf16x8*)&Ks[ts * 16 + lr][32 + lg * 8];
            f32x4 z = {0.f, 0.f, 0.f, 0.f};
            z = mfma16x16x32(qf0, kf0, z);
            z = mfma16x16x32(qf1, kf1, z);
            sc4[ts] = z;
        }
        #pragma unroll
        for (int ts = 0; ts < 4; ++ts)
            #pragma unroll
            for (int r = 0; r < 4; ++r) {
                float s = sc4[ts][r] * ASCALE;
                if (t0 + ts * 16 + lr > qr + lg * 4 + r) s = -INFINITY;
                sc4[ts][r] = s;
            }

        // online softmax (row = lg*4+r; reduce across the 16 lanes of the group)
        float mnew[4], alpha[4];
        #pragma unroll
        for (int r = 0; r < 4; ++r) {
            float rm = fmaxf(fmaxf(sc4[0][r], sc4[1][r]), fmaxf(sc4[2][r], sc4[3][r]));
            rm = fmaxf(rm, __shfl_xor(rm, 1));
            rm = fmaxf(rm, __shfl_xor(rm, 2));
            rm = fmaxf(rm, __shfl_xor(rm, 4));
            rm = fmaxf(rm, __shfl_xor(rm, 8));
            mnew[r] = fmaxf(m_run[r], rm);
            alpha[r] = __expf(m_run[r] - mnew[r]);
            m_run[r] = mnew[r];
        }
        float rs[4] = {0.f, 0.f, 0.f, 0.f};
        #pragma unroll
        for (int ts = 0; ts < 4; ++ts)
            #pragma unroll
            for (int r = 0; r < 4; ++r) {
                float pv = __expf(sc4[ts][r] - mnew[r]);
                Ps[wid][lg * 4 + r][ts * 16 + lr] = (__bf16)pv;   // C-layout -> A-layout bounce
                rs[r] += pv;
            }
        #pragma unroll
        for (int r = 0; r < 4; ++r) {
            rs[r] += __shfl_xor(rs[r], 1);
            rs[r] += __shfl_xor(rs[r], 2);
            rs[r] += __shfl_xor(rs[r], 4);
            rs[r] += __shfl_xor(rs[r], 8);
            l_run[r] = l_run[r] * alpha[r] + rs[r];
        }
        #pragma unroll
        for (int hf = 0; hf < 4; ++hf)
            #pragma unroll
            for (int r = 0; r < 4; ++r) oacc[hf][r] *= alpha[r];

        // O += P V
        bf16x8 pf0 = *(const bf16x8*)&Ps[wid][lr][lg * 8];
        bf16x8 pf1 = *(const bf16x8*)&Ps[wid][lr][32 + lg * 8];
        #pragma unroll
        for (int hf = 0; hf < 4; ++hf) {
            bf16x8 vf0 = *(const bf16x8*)&Vs[hf * 16 + lr][lg * 8];
            bf16x8 vf1 = *(const bf16x8*)&Vs[hf * 16 + lr][32 + lg * 8];
            oacc[hf] = mfma16x16x32(pf0, vf0, oacc[hf]);
            oacc[hf] = mfma16x16x32(pf1, vf1, oacc[hf]);
        }
        __syncthreads();
    }

    float inv_l[4];
    #pragma unroll
    for (int r = 0; r < 4; ++r) inv_l[r] = 1.f / l_run[r];
    #pragma unroll
    for (int hf = 0; hf < 4; ++hf)
        #pragma unroll
        for (int r = 0; r < 4; ++r)
            o[(size_t)(b * SEQ + qr + lg * 4 + r) * DMODEL + h * HD + hf * 16 + lr] =
                (__bf16)(oacc[hf][r] * inv_l[r]);
    if (lr == 0) {
        #pragma unroll
        for (int r = 0; r < 4; ++r) {
            const int row = qr + lg * 4 + r;
            mbuf[(size_t)(b * NHEAD + h) * SEQ + row] = m_run[r];
            lbuf[(size_t)(b * NHEAD + h) * SEQ + row] = l_run[r];
        }
    }
}

// mean-over-heads attention probabilities: wout[b][s][t] f32
__global__ __launch_bounds__(256) void attn_weights(const __bf16* __restrict__ q,
                                                    const __bf16* __restrict__ k,
                                                    const float* __restrict__ mbuf,
                                                    const float* __restrict__ lbuf,
                                                    float* __restrict__ wout) {
    const int tt = blockIdx.x;
    const int st = blockIdx.y;
    const int b = blockIdx.z;
    const int tid = threadIdx.x;
    const int lane = tid & 63;
    const int wid = tid >> 6;
    const int lr = lane & 15;
    const int lg = lane >> 4;
    const int q0 = st * 64;
    const int t0 = tt * 64;
    const int qr = q0 + wid * 16;

    if (tt > st) {  // strictly above the diagonal: zeros (d_out is poisoned, must write)
        #pragma unroll
        for (int ts = 0; ts < 4; ++ts)
            #pragma unroll
            for (int r = 0; r < 4; ++r)
                wout[(size_t)(b * SEQ + qr + lg * 4 + r) * SEQ + t0 + ts * 16 + lr] = 0.f;
        return;
    }

    __shared__ __bf16 Ks[64][72];
    const int srow = tid >> 2;
    const int sc0 = (tid & 3) * 16;

    f32x4 wacc[4] = {};

    for (int h = 0; h < NHEAD; ++h) {
        __syncthreads();
        const __bf16* kp = k + (size_t)(b * SEQ + t0 + srow) * DMODEL + h * HD + sc0;
        *(bf16x8*)&Ks[srow][sc0]     = ((const bf16x8*)kp)[0];
        *(bf16x8*)&Ks[srow][sc0 + 8] = ((const bf16x8*)kp)[1];
        __syncthreads();

        const __bf16* qp = q + (size_t)(b * SEQ + qr + lr) * DMODEL + h * HD + lg * 8;
        bf16x8 qf0 = ((const bf16x8*)qp)[0];
        bf16x8 qf1 = *(const bf16x8*)(qp + 32);

        float rowm[4], rowli[4];
        #pragma unroll
        for (int r = 0; r < 4; ++r) {
            const int row = qr + lg * 4 + r;
            rowm[r]  = mbuf[(size_t)(b * NHEAD + h) * SEQ + row];
            rowli[r] = 1.f / lbuf[(size_t)(b * NHEAD + h) * SEQ + row];
        }

        #pragma unroll
        for (int ts = 0; ts < 4; ++ts) {
            bf16x8 kf0 = *(const bf16x8*)&Ks[ts * 16 + lr][lg * 8];
            bf16x8 kf1 = *(const bf16x8*)&Ks[ts * 16 + lr][32 + lg * 8];
            f32x4 z = {0.f, 0.f, 0.f, 0.f};
            z = mfma16x16x32(qf0, kf0, z);
            z = mfma16x16x32(qf1, kf1, z);
            #pragma unroll
            for (int r = 0; r < 4; ++r) {
                const int tg = t0 + ts * 16 + lr;
                const int qg = qr + lg * 4 + r;
                float pr = 0.f;
                if (tg <= qg) pr = __expf(z[r] * ASCALE - rowm[r]) * rowli[r];
                wacc[ts][r] += pr;
            }
        }
    }
    #pragma unroll
    for (int ts = 0; ts < 4; ++ts)
        #pragma unroll
        for (int r = 0; r < 4; ++r)
            wout[(size_t)(b * SEQ + qr + lg * 4 + r) * SEQ + t0 + ts * 16 + lr] =
                wacc[ts][r] * (1.f / NHEAD);
}

extern "C" void kernel_launch(void* const* d_in, const int* in_sizes, int n_in,
                              void* d_out, int out_size, void* d_ws, size_t ws_size,
                              hipStream_t stream) {
    const float* query = (const float*)d_in[0];
    const float* key_  = (const float*)d_in[1];
    const float* value = (const float*)d_in[2];
    const float* Wq = (const float*)d_in[3];
    const float* bq = (const float*)d_in[4];
    const float* Wk = (const float*)d_in[5];
    const float* bk = (const float*)d_in[6];
    const float* Wv = (const float*)d_in[7];
    const float* bv = (const float*)d_in[8];
    const float* Wo = (const float*)d_in[9];
    const float* bo = (const float*)d_in[10];
    float* out = (float*)d_out;

    char* p = (char*)d_ws;
    const size_t mat = (size_t)BC * SEQ * DMODEL * sizeof(__bf16);
    __bf16* qb  = (__bf16*)p; p += mat;
    __bf16* kb  = (__bf16*)p; p += mat;
    __bf16* vb  = (__bf16*)p; p += mat;
    __bf16* vtb = (__bf16*)p; p += mat;
    __bf16* ob  = (__bf16*)p; p += mat;
    float* mb = (float*)p; p += (size_t)BC * NHEAD * SEQ * sizeof(float);
    float* lb = (float*)p; p += (size_t)BC * NHEAD * SEQ * sizeof(float);

    const int M = BC * SEQ;
    dim3 gg(M / 128, DMODEL / 128);
    gemm_bt<float, __bf16><<<gg, 256, 0, stream>>>(query, Wq, bq, qb, M, DMODEL, DMODEL);
    gemm_bt<float, __bf16><<<gg, 256, 0, stream>>>(key_,  Wk, bk, kb, M, DMODEL, DMODEL);
    gemm_bt<float, __bf16><<<gg, 256, 0, stream>>>(value, Wv, bv, vb, M, DMODEL, DMODEL);
    transpose_v<<<dim3(SEQ / 64, NHEAD, BC), 256, 0, stream>>>(vb, vtb);
    flash_fwd<<<dim3(SEQ / 64, NHEAD, BC), 256, 0, stream>>>(qb, kb, vtb, ob, mb, lb);
    gemm_bt<__bf16, float><<<gg, 256, 0, stream>>>(ob, Wo, bo, out, M, DMODEL, DMODEL);
    float* wout = out + (size_t)BC * SEQ * DMODEL;
    attn_weights<<<dim3(SEQ / 64, SEQ / 64, BC), 256, 0, stream>>>(qb, kb, mb, lb, wout);
}

// Round 2
// 468.583 us; speedup vs baseline: 1.1505x; 1.1505x over previous
//
#include <hip/hip_runtime.h>
#include <hip/hip_bf16.h>
#include <cmath>
#include <type_traits>

#define BC     4
#define SEQ    2048
#define DMODEL 1024
#define NHEAD  16
#define HD     64
#define ASCALE 0.125f

typedef __bf16 bf16x8 __attribute__((ext_vector_type(8)));
typedef __bf16 bf16x4 __attribute__((ext_vector_type(4)));
typedef float  f32x4  __attribute__((ext_vector_type(4)));

__device__ __forceinline__ f32x4 mfma16x16x32(bf16x8 a, bf16x8 b, f32x4 c) {
    return __builtin_amdgcn_mfma_f32_16x16x32_bf16(a, b, c, 0, 0, 0);
}

// out[M,N] = A[M,K] @ W[N,K]^T + bias[N].  TA in {float,__bf16}, TO in {__bf16,float}.
template <typename TA, typename TO>
__global__ __launch_bounds__(256) void gemm_bt(const TA* __restrict__ A,
                                               const float* __restrict__ W,
                                               const float* __restrict__ bias,
                                               TO* __restrict__ out,
                                               int M, int N, int K) {
    __shared__ __bf16 As[128][40];   // stride 40 (80B): 16B-aligned rows, 2-way banks = free
    __shared__ __bf16 Bs[128][40];
    const int tid = threadIdx.x;
    const int lane = tid & 63;
    const int wid = tid >> 6;
    const int lr = lane & 15;
    const int lg = lane >> 4;
    const int wr = (wid >> 1) * 64;
    const int wc = (wid & 1) * 64;
    const int bm = blockIdx.x * 128;
    const int bn = blockIdx.y * 128;
    const int srow = tid >> 1;
    const int scol = (tid & 1) * 16;

    f32x4 acc[4][4] = {};

    for (int k0 = 0; k0 < K; k0 += 32) {
        bf16x8 a0, a1;
        if constexpr (std::is_same_v<TA, float>) {
            const float* ap = (const float*)A + (size_t)(bm + srow) * K + k0 + scol;
            float4 f0 = ((const float4*)ap)[0];
            float4 f1 = ((const float4*)ap)[1];
            float4 f2 = ((const float4*)ap)[2];
            float4 f3 = ((const float4*)ap)[3];
            a0[0] = (__bf16)f0.x; a0[1] = (__bf16)f0.y; a0[2] = (__bf16)f0.z; a0[3] = (__bf16)f0.w;
            a0[4] = (__bf16)f1.x; a0[5] = (__bf16)f1.y; a0[6] = (__bf16)f1.z; a0[7] = (__bf16)f1.w;
            a1[0] = (__bf16)f2.x; a1[1] = (__bf16)f2.y; a1[2] = (__bf16)f2.z; a1[3] = (__bf16)f2.w;
            a1[4] = (__bf16)f3.x; a1[5] = (__bf16)f3.y; a1[6] = (__bf16)f3.z; a1[7] = (__bf16)f3.w;
        } else {
            const __bf16* ap = (const __bf16*)A + (size_t)(bm + srow) * K + k0 + scol;
            a0 = ((const bf16x8*)ap)[0];
            a1 = ((const bf16x8*)ap)[1];
        }
        const float* wp = W + (size_t)(bn + srow) * K + k0 + scol;
        float4 g0 = ((const float4*)wp)[0];
        float4 g1 = ((const float4*)wp)[1];
        float4 g2 = ((const float4*)wp)[2];
        float4 g3 = ((const float4*)wp)[3];
        bf16x8 b0, b1;
        b0[0] = (__bf16)g0.x; b0[1] = (__bf16)g0.y; b0[2] = (__bf16)g0.z; b0[3] = (__bf16)g0.w;
        b0[4] = (__bf16)g1.x; b0[5] = (__bf16)g1.y; b0[6] = (__bf16)g1.z; b0[7] = (__bf16)g1.w;
        b1[0] = (__bf16)g2.x; b1[1] = (__bf16)g2.y; b1[2] = (__bf16)g2.z; b1[3] = (__bf16)g2.w;
        b1[4] = (__bf16)g3.x; b1[5] = (__bf16)g3.y; b1[6] = (__bf16)g3.z; b1[7] = (__bf16)g3.w;

        *(bf16x8*)&As[srow][scol]     = a0;
        *(bf16x8*)&As[srow][scol + 8] = a1;
        *(bf16x8*)&Bs[srow][scol]     = b0;
        *(bf16x8*)&Bs[srow][scol + 8] = b1;

        __syncthreads();

        bf16x8 af[4], bfg[4];
        #pragma unroll
        for (int m = 0; m < 4; ++m)
            af[m] = *(const bf16x8*)&As[wr + m * 16 + lr][lg * 8];
        #pragma unroll
        for (int n = 0; n < 4; ++n)
            bfg[n] = *(const bf16x8*)&Bs[wc + n * 16 + lr][lg * 8];
        #pragma unroll
        for (int m = 0; m < 4; ++m)
            #pragma unroll
            for (int n = 0; n < 4; ++n)
                acc[m][n] = mfma16x16x32(af[m], bfg[n], acc[m][n]);
        __syncthreads();
    }

    #pragma unroll
    for (int n = 0; n < 4; ++n) {
        const int col = bn + wc + n * 16 + lr;
        const float bb = bias[col];
        #pragma unroll
        for (int m = 0; m < 4; ++m) {
            const int row = bm + wr + m * 16 + lg * 4;
            #pragma unroll
            for (int r = 0; r < 4; ++r) {
                float val = acc[m][n][r] + bb;
                out[(size_t)(row + r) * N + col] = (TO)val;
            }
        }
    }
}

// vt[b][h][hd][s] = v[b][s][h*64+hd]
__global__ __launch_bounds__(256) void transpose_v(const __bf16* __restrict__ v,
                                                   __bf16* __restrict__ vt) {
    __shared__ __bf16 T[64][72];
    const int tid = threadIdx.x;
    const int s0 = blockIdx.x * 64;
    const int h = blockIdx.y;
    const int b = blockIdx.z;
    const int r = tid >> 2;
    const int c0 = (tid & 3) * 16;
    const __bf16* vp = v + (size_t)(b * SEQ + s0 + r) * DMODEL + h * HD + c0;
    *(bf16x8*)&T[r][c0]     = ((const bf16x8*)vp)[0];
    *(bf16x8*)&T[r][c0 + 8] = ((const bf16x8*)vp)[1];
    __syncthreads();
    const int hd = tid >> 2;
    const int sc = (tid & 3) * 16;
    bf16x8 o0, o1;
    #pragma unroll
    for (int j = 0; j < 8; ++j) o0[j] = T[sc + j][hd];
    #pragma unroll
    for (int j = 0; j < 8; ++j) o1[j] = T[sc + 8 + j][hd];
    __bf16* op = vt + ((size_t)(b * NHEAD + h) * HD + hd) * SEQ + s0 + sc;
    ((bf16x8*)op)[0] = o0;
    ((bf16x8*)op)[1] = o1;
}

// Causal flash attention, swapped-QK in-register softmax.
// q,k: [B,S,D] bf16 (head-interleaved). vt: [B,H,HD,S] bf16.
// o: [B,S,D] bf16. mbuf/lbuf: [B,H,S] f32 row stats for the weights pass.
__global__ __launch_bounds__(256) void flash_fwd(const __bf16* __restrict__ q,
                                                 const __bf16* __restrict__ k,
                                                 const __bf16* __restrict__ vt,
                                                 __bf16* __restrict__ o,
                                                 float* __restrict__ mbuf,
                                                 float* __restrict__ lbuf) {
    __shared__ __bf16 Ks[64][72];
    __shared__ __bf16 Vs[64][72];   // transposed: [hd][t]
    __shared__ __bf16 Ps[4][16][72];
    const int tid = threadIdx.x;
    const int lane = tid & 63;
    const int wid = tid >> 6;
    const int lr = lane & 15;
    const int lg = lane >> 4;
    const int qt = (int)gridDim.x - 1 - (int)blockIdx.x;  // heavy blocks dispatch first
    const int h = blockIdx.y;
    const int b = blockIdx.z;
    const int q0 = qt * 64;
    const int qr = q0 + wid * 16;   // this wave's 16 query rows
    const int myq = qr + lr;        // this lane's q row (swapped layout: q = lane&15)

    // Q fragment (used as the MFMA *B* operand): rows of Q, k-dim = head dim
    bf16x8 qf0, qf1;
    {
        const __bf16* qp = q + (size_t)(b * SEQ + myq) * DMODEL + h * HD + lg * 8;
        qf0 = ((const bf16x8*)qp)[0];
        qf1 = *(const bf16x8*)(qp + 32);
    }

    float m_run = -INFINITY;  // running max for row `myq`
    float l_run = 0.f;        // running denom for row `myq`
    f32x4 oacc[4] = {};       // O[q=qr+lg*4+r][hd=hf*16+lr]

    const int srow = tid >> 2;
    const int sc0 = (tid & 3) * 16;
    const int nt = qt + 1;

    // prologue: prefetch tile 0 into registers
    bf16x8 kr0, kr1, vr0, vr1;
    {
        const __bf16* kp = k + (size_t)(b * SEQ + srow) * DMODEL + h * HD + sc0;
        kr0 = ((const bf16x8*)kp)[0];
        kr1 = ((const bf16x8*)kp)[1];
        const __bf16* vp = vt + ((size_t)(b * NHEAD + h) * HD + srow) * SEQ + sc0;
        vr0 = ((const bf16x8*)vp)[0];
        vr1 = ((const bf16x8*)vp)[1];
    }

    for (int t = 0; t < nt; ++t) {
        const int t0 = t * 64;
        // commit prefetched tile to LDS
        *(bf16x8*)&Ks[srow][sc0]     = kr0;
        *(bf16x8*)&Ks[srow][sc0 + 8] = kr1;
        *(bf16x8*)&Vs[srow][sc0]     = vr0;
        *(bf16x8*)&Vs[srow][sc0 + 8] = vr1;
        __syncthreads();

        // prefetch next tile (HBM latency hides under QK+softmax+PV)
        if (t + 1 < nt) {
            const int t1 = t0 + 64;
            const __bf16* kp = k + (size_t)(b * SEQ + t1 + srow) * DMODEL + h * HD + sc0;
            kr0 = ((const bf16x8*)kp)[0];
            kr1 = ((const bf16x8*)kp)[1];
            const __bf16* vp = vt + ((size_t)(b * NHEAD + h) * HD + srow) * SEQ + t1 + sc0;
            vr0 = ((const bf16x8*)vp)[0];
            vr1 = ((const bf16x8*)vp)[1];
        }

        // S^T = K Q^T * scale: lane holds S[myq][t0 + ts*16 + lg*4 + r]
        f32x4 z[4];
        #pragma unroll
        for (int ts = 0; ts < 4; ++ts) {
            bf16x8 kf0 = *(const bf16x8*)&Ks[ts * 16 + lr][lg * 8];
            bf16x8 kf1 = *(const bf16x8*)&Ks[ts * 16 + lr][32 + lg * 8];
            f32x4 acc = {0.f, 0.f, 0.f, 0.f};
            acc = mfma16x16x32(kf0, qf0, acc);
            acc = mfma16x16x32(kf1, qf1, acc);
            z[ts] = acc;
        }
        #pragma unroll
        for (int ts = 0; ts < 4; ++ts)
            #pragma unroll
            for (int r = 0; r < 4; ++r) {
                float s = z[ts][r] * ASCALE;
                if (t0 + ts * 16 + lg * 4 + r > myq) s = -INFINITY;
                z[ts][r] = s;
            }

        // in-register row softmax: 16 values in-lane, 2 shfls across lg
        float mt = z[0][0];
        #pragma unroll
        for (int ts = 0; ts < 4; ++ts)
            #pragma unroll
            for (int r = 0; r < 4; ++r) mt = fmaxf(mt, z[ts][r]);
        mt = fmaxf(mt, __shfl_xor(mt, 16));
        mt = fmaxf(mt, __shfl_xor(mt, 32));
        const float mnew = fmaxf(m_run, mt);
        const float alpha = __expf(m_run - mnew);
        m_run = mnew;

        float rsum = 0.f;
        #pragma unroll
        for (int ts = 0; ts < 4; ++ts) {
            bf16x4 pk;
            #pragma unroll
            for (int r = 0; r < 4; ++r) {
                float pv = __expf(z[ts][r] - mnew);
                rsum += pv;
                pk[r] = (__bf16)pv;
            }
            *(bf16x4*)&Ps[wid][lr][ts * 16 + lg * 4] = pk;   // packed b64 store
        }
        rsum += __shfl_xor(rsum, 16);
        rsum += __shfl_xor(rsum, 32);
        l_run = l_run * alpha + rsum;

        // rescale O: oacc rows are q = qr + lg*4 + r; alpha lives at lane lg*4+r
        #pragma unroll
        for (int r = 0; r < 4; ++r) {
            const float ar = __shfl(alpha, lg * 4 + r);
            #pragma unroll
            for (int hf = 0; hf < 4; ++hf) oacc[hf][r] *= ar;
        }

        // O += P V
        bf16x8 pf0 = *(const bf16x8*)&Ps[wid][lr][lg * 8];
        bf16x8 pf1 = *(const bf16x8*)&Ps[wid][lr][32 + lg * 8];
        #pragma unroll
        for (int hf = 0; hf < 4; ++hf) {
            bf16x8 vf0 = *(const bf16x8*)&Vs[hf * 16 + lr][lg * 8];
            bf16x8 vf1 = *(const bf16x8*)&Vs[hf * 16 + lr][32 + lg * 8];
            oacc[hf] = mfma16x16x32(pf0, vf0, oacc[hf]);
            oacc[hf] = mfma16x16x32(pf1, vf1, oacc[hf]);
        }
        __syncthreads();
    }

    const float linv = 1.f / l_run;   // for row myq
    #pragma unroll
    for (int r = 0; r < 4; ++r) {
        const float li = __shfl(linv, lg * 4 + r);
        #pragma unroll
        for (int hf = 0; hf < 4; ++hf)
            o[(size_t)(b * SEQ + qr + lg * 4 + r) * DMODEL + h * HD + hf * 16 + lr] =
                (__bf16)(oacc[hf][r] * li);
    }
    if (lg == 0) {
        mbuf[(size_t)(b * NHEAD + h) * SEQ + myq] = m_run;
        lbuf[(size_t)(b * NHEAD + h) * SEQ + myq] = l_run;
    }
}

// mean-over-heads attention probabilities: wout[b][s][t] f32
__global__ __launch_bounds__(256) void attn_weights(const __bf16* __restrict__ q,
                                                    const __bf16* __restrict__ k,
                                                    const float* __restrict__ mbuf,
                                                    const float* __restrict__ lbuf,
                                                    float* __restrict__ wout) {
    const int tt = blockIdx.x;
    const int st = blockIdx.y;
    const int b = blockIdx.z;
    const int tid = threadIdx.x;
    const int lane = tid & 63;
    const int wid = tid >> 6;
    const int lr = lane & 15;
    const int lg = lane >> 4;
    const int q0 = st * 64;
    const int t0 = tt * 64;
    const int qr = q0 + wid * 16;

    if (tt > st) {  // strictly above the diagonal: zeros (d_out is poisoned, must write)
        #pragma unroll
        for (int ts = 0; ts < 4; ++ts)
            #pragma unroll
            for (int r = 0; r < 4; ++r)
                wout[(size_t)(b * SEQ + qr + lg * 4 + r) * SEQ + t0 + ts * 16 + lr] = 0.f;
        return;
    }

    __shared__ __bf16 Ks[64][72];
    const int srow = tid >> 2;
    const int sc0 = (tid & 3) * 16;

    f32x4 wacc[4] = {};

    for (int h = 0; h < NHEAD; ++h) {
        __syncthreads();
        const __bf16* kp = k + (size_t)(b * SEQ + t0 + srow) * DMODEL + h * HD + sc0;
        *(bf16x8*)&Ks[srow][sc0]     = ((const bf16x8*)kp)[0];
        *(bf16x8*)&Ks[srow][sc0 + 8] = ((const bf16x8*)kp)[1];
        __syncthreads();

        const __bf16* qp = q + (size_t)(b * SEQ + qr + lr) * DMODEL + h * HD + lg * 8;
        bf16x8 qf0 = ((const bf16x8*)qp)[0];
        bf16x8 qf1 = *(const bf16x8*)(qp + 32);

        float rowm[4], rowli[4];
        #pragma unroll
        for (int r = 0; r < 4; ++r) {
            const int row = qr + lg * 4 + r;
            rowm[r]  = mbuf[(size_t)(b * NHEAD + h) * SEQ + row];
            rowli[r] = 1.f / lbuf[(size_t)(b * NHEAD + h) * SEQ + row];
        }

        #pragma unroll
        for (int ts = 0; ts < 4; ++ts) {
            bf16x8 kf0 = *(const bf16x8*)&Ks[ts * 16 + lr][lg * 8];
            bf16x8 kf1 = *(const bf16x8*)&Ks[ts * 16 + lr][32 + lg * 8];
            f32x4 zz = {0.f, 0.f, 0.f, 0.f};
            zz = mfma16x16x32(qf0, kf0, zz);
            zz = mfma16x16x32(qf1, kf1, zz);
            #pragma unroll
            for (int r = 0; r < 4; ++r) {
                const int tg = t0 + ts * 16 + lr;
                const int qg = qr + lg * 4 + r;
                float pr = 0.f;
                if (tg <= qg) pr = __expf(zz[r] * ASCALE - rowm[r]) * rowli[r];
                wacc[ts][r] += pr;
            }
        }
    }
    #pragma unroll
    for (int ts = 0; ts < 4; ++ts)
        #pragma unroll
        for (int r = 0; r < 4; ++r)
            wout[(size_t)(b * SEQ + qr + lg * 4 + r) * SEQ + t0 + ts * 16 + lr] =
                wacc[ts][r] * (1.f / NHEAD);
}

extern "C" void kernel_launch(void* const* d_in, const int* in_sizes, int n_in,
                              void* d_out, int out_size, void* d_ws, size_t ws_size,
                              hipStream_t stream) {
    const float* query = (const float*)d_in[0];
    const float* key_  = (const float*)d_in[1];
    const float* value = (const float*)d_in[2];
    const float* Wq = (const float*)d_in[3];
    const float* bq = (const float*)d_in[4];
    const float* Wk = (const float*)d_in[5];
    const float* bk = (const float*)d_in[6];
    const float* Wv = (const float*)d_in[7];
    const float* bv = (const float*)d_in[8];
    const float* Wo = (const float*)d_in[9];
    const float* bo = (const float*)d_in[10];
    float* out = (float*)d_out;

    char* p = (char*)d_ws;
    const size_t mat = (size_t)BC * SEQ * DMODEL * sizeof(__bf16);
    __bf16* qb  = (__bf16*)p; p += mat;
    __bf16* kb  = (__bf16*)p; p += mat;
    __bf16* vb  = (__bf16*)p; p += mat;
    __bf16* vtb = (__bf16*)p; p += mat;
    __bf16* ob  = (__bf16*)p; p += mat;
    float* mb = (float*)p; p += (size_t)BC * NHEAD * SEQ * sizeof(float);
    float* lb = (float*)p; p += (size_t)BC * NHEAD * SEQ * sizeof(float);

    const int M = BC * SEQ;
    dim3 gg(M / 128, DMODEL / 128);
    gemm_bt<float, __bf16><<<gg, 256, 0, stream>>>(query, Wq, bq, qb, M, DMODEL, DMODEL);
    gemm_bt<float, __bf16><<<gg, 256, 0, stream>>>(key_,  Wk, bk, kb, M, DMODEL, DMODEL);
    gemm_bt<float, __bf16><<<gg, 256, 0, stream>>>(value, Wv, bv, vb, M, DMODEL, DMODEL);
    transpose_v<<<dim3(SEQ / 64, NHEAD, BC), 256, 0, stream>>>(vb, vtb);
    flash_fwd<<<dim3(SEQ / 64, NHEAD, BC), 256, 0, stream>>>(qb, kb, vtb, ob, mb, lb);
    gemm_bt<__bf16, float><<<gg, 256, 0, stream>>>(ob, Wo, bo, out, M, DMODEL, DMODEL);
    float* wout = out + (size_t)BC * SEQ * DMODEL;
    attn_weights<<<dim3(SEQ / 64, SEQ / 64, BC), 256, 0, stream>>>(qb, kb, mb, lb, wout);
}